// Round 6
// baseline (329.870 us; speedup 1.0000x reference)
//
#include <hip/hip_runtime.h>

#define NN   131072      // nodes
#define GG   8192        // graphs
#define EE   2097152     // edges
#define KBIG 16384       // (2*GS)^2
#define NPAD 224         // 200 padded to 14*16 (2 waves x 7 nt)
#define NSPLIT 8
#define NSEL  16384      // selected slots (2 per graph)
#define SBUCK 256        // slot buckets of 64 slots
#define SUBC  4          // sub-counters per bucket (atomic spread)
#define SCAPS 336        // per-sub capacity (mean ~237 + 6.4 sigma)
#define SCAPT (SUBC*SCAPS)  // 1344 per bucket

typedef _Float16 half_t;
typedef __attribute__((ext_vector_type(8))) _Float16 half8;
typedef __attribute__((ext_vector_type(4))) float floatx4;

__device__ inline floatx4 mfma16(half8 a, half8 b, floatx4 c) {
  return __builtin_amdgcn_mfma_f32_16x16x32_f16(a, b, c, 0, 0, 0);
}

// ---------------- prep kernels ----------------
// Wt[n][k] (n-major, f16): n<64 -> W_l[k][n], n>=64 -> W_r[k][n-64]
__global__ void prep_w(const float* __restrict__ Wl, const float* __restrict__ Wr,
                       half_t* __restrict__ Wt) {
  int idx = blockIdx.x * blockDim.x + threadIdx.x; // 128*128
  int n = idx >> 7, k = idx & 127;
  float v = (n < 64) ? Wl[k * 64 + n] : Wr[k * 64 + (n - 64)];
  Wt[n * 128 + k] = (half_t)v;
}
// W1p packed fragment-order for phase-split K:
// frag = (((split*2+ph)*16 + i)*2 + jj)*14 + nt ; within frag: lane, 8 elems
// k = split*2048 + i*128 + ph*64 + jj*32 + (lane>>4)*8 + e ; n = nt*16 + (lane&15)
__global__ void prep_w1p(const float* __restrict__ W1, half_t* __restrict__ W1p) {
  int idx = blockIdx.x * blockDim.x + threadIdx.x; // 8*2*16*2*14*64 = 458752
  int lane = idx & 63;
  int t = idx >> 6;
  int nt = t % 14; t /= 14;
  int jj = t & 1;  t >>= 1;
  int i  = t & 15; t >>= 4;
  int ph = t & 1;  t >>= 1;
  int split = t;
  int n = nt * 16 + (lane & 15);
  int k0 = split * 2048 + i * 128 + ph * 64 + jj * 32 + (lane >> 4) * 8;
  half8 v;
#pragma unroll
  for (int e = 0; e < 8; e++)
    v[e] = (half_t)((n < 200) ? W1[(size_t)(k0 + e) * 200 + n] : 0.f);
  *(half8*)(W1p + (size_t)idx * 8) = v;
}

// ---------------- selected-node slot map ----------------
__global__ void set_slots(const int* __restrict__ set_idx, int* __restrict__ nodemap,
                          int* __restrict__ slot_node) {
  int idx = blockIdx.x * blockDim.x + threadIdx.x;   // 16384
  int g = idx >> 1, which = idx & 1;
  int node = g * 16 + set_idx[g * 2 + which];
  slot_node[idx] = node;
  nodemap[node] = idx;
}

// ---------------- filtered edge scatter (only edges into selected nodes) ----------------
__global__ void filter_scatter(const int* __restrict__ src, const int* __restrict__ dst,
                               const int* __restrict__ nodemap,
                               int* __restrict__ scnt, unsigned int* __restrict__ sbuf) {
  int e = blockIdx.x * blockDim.x + threadIdx.x;
  int d = dst[e];
  int slot = nodemap[d];
  if (slot >= 0) {
    int b = slot >> 6;
    int sub = blockIdx.x & (SUBC - 1);
    int pos = atomicAdd(&scnt[(b * SUBC + sub) * 16], 1);
    if (pos < SCAPS)
      sbuf[(size_t)(b * SUBC + sub) * SCAPS + pos] =
          (unsigned int)src[e] | ((unsigned int)(slot & 63) << 17);
  }
}

// ---------------- y = x@W_l only (r is computed per-slot in r_slots) ----------------
__global__ __launch_bounds__(256) void y_gemm(const float* __restrict__ x,
                                              const half_t* __restrict__ WtG,
                                              half_t* __restrict__ y16) {
  __shared__ half_t wlds[64 * 128];   // W_l rows 0..63, 16 KB
  __shared__ half_t ybuf[64 * 72];    // transpose buffer, stride 72 (16B-aligned rows)
  int tid = threadIdx.x, w = tid >> 6, lane = tid & 63;
  int m = lane & 15, q = lane >> 4, kc = q * 8;
#pragma unroll
  for (int it = 0; it < 4; it++) {
    int cb = (it * 4 + w) * 64;       // chunk base for this wave
    const half_t* g = WtG + ((size_t)cb + lane) * 8;
    half_t* l = wlds + (size_t)cb * 8;
    __builtin_amdgcn_global_load_lds((const __attribute__((address_space(1))) uint32_t*)g,
                                     (__attribute__((address_space(3))) uint32_t*)l, 16, 0, 0);
  }
  int node0 = blockIdx.x * 64 + w * 16;
  float4 xu[4][2];
#pragma unroll
  for (int step = 0; step < 4; step++) {
    const float* xp = x + (size_t)(node0 + m) * 128 + step * 32 + kc;
    xu[step][0] = *(const float4*)xp;
    xu[step][1] = *(const float4*)(xp + 4);
  }
  __syncthreads();                    // wlds ready (barrier drains vmcnt)
  floatx4 acc[4];
#pragma unroll
  for (int nt = 0; nt < 4; nt++) acc[nt] = (floatx4){0.f, 0.f, 0.f, 0.f};
#pragma unroll
  for (int step = 0; step < 4; step++) {
    float4 u0 = xu[step][0], u1 = xu[step][1];
    half8 av = {(half_t)u0.x, (half_t)u0.y, (half_t)u0.z, (half_t)u0.w,
                (half_t)u1.x, (half_t)u1.y, (half_t)u1.z, (half_t)u1.w};
    int k0 = step * 32 + kc;
#pragma unroll
    for (int nt = 0; nt < 4; nt++) {
      half8 bv = *(const half8*)(wlds + (nt * 16 + m) * 128 + k0);
      acc[nt] = mfma16(av, bv, acc[nt]);
    }
  }
#pragma unroll
  for (int nt = 0; nt < 4; nt++)
#pragma unroll
    for (int r = 0; r < 4; r++)
      ybuf[(w * 16 + q * 4 + r) * 72 + nt * 16 + m] = (half_t)acc[nt][r];
  __syncthreads();
#pragma unroll
  for (int c = tid; c < 512; c += 256) {
    int row = c >> 3, co = (c & 7) * 8;
    *(half8*)(y16 + (size_t)(blockIdx.x * 64 + row) * 64 + co) =
        *(const half8*)(ybuf + row * 72 + co);
  }
}

// ---------------- r_slot[slot] = x[slot_node[slot]] @ W_r + b_l (16384 slots only) ----------------
__global__ __launch_bounds__(256) void r_slots(const float* __restrict__ x,
                                               const half_t* __restrict__ WtG,
                                               const float* __restrict__ b_l,
                                               const int* __restrict__ slot_node,
                                               half_t* __restrict__ r_slot) {
  int tid = threadIdx.x, w = tid >> 6, lane = tid & 63;
  int m = lane & 15, q = lane >> 4, kc = q * 8;
  int s0 = blockIdx.x * 64 + w * 16;   // 16 slots per wave
  int node = slot_node[s0 + m];
  floatx4 acc[4];
#pragma unroll
  for (int nt = 0; nt < 4; nt++) acc[nt] = (floatx4){0.f, 0.f, 0.f, 0.f};
#pragma unroll
  for (int step = 0; step < 4; step++) {
    int k0 = step * 32 + kc;
    const float* xp = x + (size_t)node * 128 + k0;
    float4 u0 = *(const float4*)xp;
    float4 u1 = *(const float4*)(xp + 4);
    half8 av = {(half_t)u0.x, (half_t)u0.y, (half_t)u0.z, (half_t)u0.w,
                (half_t)u1.x, (half_t)u1.y, (half_t)u1.z, (half_t)u1.w};
#pragma unroll
    for (int nt = 0; nt < 4; nt++) {
      half8 bv = *(const half8*)(WtG + (size_t)(64 + nt * 16 + m) * 128 + k0);
      acc[nt] = mfma16(av, bv, acc[nt]);
    }
  }
#pragma unroll
  for (int nt = 0; nt < 4; nt++) {
    int n = nt * 16 + m;
    float bias = b_l[n];
#pragma unroll
    for (int r = 0; r < 4; r++) {
      int s = s0 + q * 4 + r;
      r_slot[(size_t)s * 64 + n] = (half_t)(acc[nt][r] + bias);
    }
  }
}

// ---------------- per-slot SAGE agg: LDS counting sort + register accumulation ----------------
__global__ __launch_bounds__(256) void slot_agg(const unsigned int* __restrict__ sbuf,
                                                const int* __restrict__ scnt,
                                                const half_t* __restrict__ y16,
                                                const half_t* __restrict__ r_slot,
                                                half_t* __restrict__ h_slot) {
  __shared__ int sorted[SCAPT];    // src indices, grouped by local slot
  __shared__ int hist[64];
  __shared__ int base[64];
  __shared__ int start[65];
  int b = blockIdx.x, tid = threadIdx.x;
  if (tid < 64) hist[tid] = 0;
  __syncthreads();
  unsigned int myedge[2 * SUBC];
  int mycnt = 0;
#pragma unroll
  for (int sub = 0; sub < SUBC; sub++) {
    int n = scnt[(b * SUBC + sub) * 16]; if (n > SCAPS) n = SCAPS;
    const unsigned int* eb = sbuf + (size_t)(b * SUBC + sub) * SCAPS;
    for (int e = tid; e < n; e += 256) {
      unsigned int pk = eb[e];
      myedge[mycnt++] = pk;
      atomicAdd(&hist[pk >> 17], 1);
    }
  }
  __syncthreads();
  if (tid < 64) {                       // wave 0: exclusive scan of 64 bins
    int v = hist[tid];
    int sum = v;
#pragma unroll
    for (int off = 1; off < 64; off <<= 1) {
      int u = __shfl_up(sum, off);
      if (tid >= off) sum += u;
    }
    start[tid] = sum - v;
    base[tid]  = sum - v;
    if (tid == 63) start[64] = sum;
  }
  __syncthreads();
  for (int i = 0; i < mycnt; i++) {
    unsigned int pk = myedge[i];
    int pos = atomicAdd(&base[pk >> 17], 1);
    sorted[pos] = (int)(pk & 0x1FFFF);
  }
  __syncthreads();
  int s = tid >> 2, p = tid & 3;
  int e0 = start[s], e1 = start[s + 1];
  float acc[16];
#pragma unroll
  for (int j = 0; j < 16; j++) acc[j] = 0.f;
  int e = e0;
  for (; e + 2 <= e1; e += 2) {
    int s0 = sorted[e], s1 = sorted[e + 1];
    const half8* p0 = (const half8*)(y16 + (size_t)s0 * 64 + p * 16);
    const half8* p1 = (const half8*)(y16 + (size_t)s1 * 64 + p * 16);
    half8 a0 = p0[0], c0 = p0[1], a1 = p1[0], c1 = p1[1];
#pragma unroll
    for (int j = 0; j < 8; j++) {
      acc[j]     += (float)a0[j] + (float)a1[j];
      acc[8 + j] += (float)c0[j] + (float)c1[j];
    }
  }
  if (e < e1) {
    int s0 = sorted[e];
    const half8* p0 = (const half8*)(y16 + (size_t)s0 * 64 + p * 16);
    half8 a0 = p0[0], c0 = p0[1];
#pragma unroll
    for (int j = 0; j < 8; j++) { acc[j] += (float)a0[j]; acc[8 + j] += (float)c0[j]; }
  }
  int slot = b * 64 + s;
  float inv = 1.0f / fmaxf((float)(e1 - e0), 1.0f);
  const half8* rr = (const half8*)(r_slot + (size_t)slot * 64 + p * 16);
  half8 r0 = rr[0], r1 = rr[1];
  half8 o0, o1;
#pragma unroll
  for (int j = 0; j < 8; j++) {
    o0[j] = (half_t)fmaxf(acc[j] * inv + (float)r0[j], 0.f);
    o1[j] = (half_t)fmaxf(acc[8 + j] * inv + (float)r1[j], 0.f);
  }
  half8* hp = (half8*)(h_slot + (size_t)slot * 64 + p * 16);
  hp[0] = o0;
  hp[1] = o1;
}

// ---------------- S = relu(ir @ W_ir + b_ir) and pair gather from h_slot ----------------
__global__ void s_pair_kernel(const float* __restrict__ ir, const float* __restrict__ W_ir,
                              const float* __restrict__ b_ir, half_t* __restrict__ S16,
                              const half_t* __restrict__ h_slot,
                              const int* __restrict__ nodemap,
                              const int* __restrict__ set_idx, half_t* __restrict__ pair16) {
  int idx = blockIdx.x * blockDim.x + threadIdx.x; // G*128
  int g = idx >> 7, o = idx & 127;
  const float* irow = ir + g * 32;
  float sv = b_ir[o];
#pragma unroll
  for (int a = 0; a < 32; a++) sv += irow[a] * W_ir[a * 128 + o];
  S16[idx] = (half_t)fmaxf(sv, 0.f);
  int which = o >> 6, c = o & 63;
  int node = g * 16 + set_idx[g * 2 + which];
  int slot = nodemap[node];
  pair16[idx] = h_slot[(size_t)slot * 64 + c];
}

// ---------------- z-partials: (pair(x)S) @ W1, split-K=8, BM=128 ----------------
// Register-direct B streaming: each wave loads its own 7 W1p fragments per jj-unit
// straight L2->VGPR (global_load_dwordx4, 1KB coalesced) with a pbA/pbB software
// double-buffer. NO barriers / NO LDS / NO DMA in the main loop -- removes the
// 32x per-step {syncthreads + vmcnt(0) drain + 8-wave convergence} fabric that
// round-5 accounting showed was the wall (all pipes <40% busy). Cost: W1p L2 reads
// duplicate across wm (114MB/XCD ~ 25us L2-BW floor). Regs: acc 112 + pb 2x28 +
// sf 32 + temps ~= 230 < 256 (round-5 pressure discipline; spill shows in FETCH/WRITE).
__global__ __launch_bounds__(256, 2) void biggemm(const half_t* __restrict__ pair16,
                                                  const half_t* __restrict__ S16,
                                                  const half_t* __restrict__ W1p,
                                                  float* __restrict__ zpart) {
  __shared__ half_t pls[16][128];                      // 4096 B (only LDS left)
  int bx = blockIdx.x;
  int mt = bx >> 3, split = bx & 7;   // split == XCD id -> W1 slice L2-resident per XCD
  int g0 = mt * 128;
  int tid = threadIdx.x, w = tid >> 6, lane = tid & 63;
  int wm = w >> 1, wn = w & 1;        // 2x2 wave grid
  int m = lane & 15, q = lane >> 4, kc = q * 8;
  int ntb = wn * 7;                   // this wave's nt base (7 nt groups)

  {
    int row = tid & 127, sel = tid >> 7;
    half8 pa = *(const half8*)(pair16 + (size_t)(g0 + row) * 128 + split * 16 + sel * 8);
#pragma unroll
    for (int j = 0; j < 8; j++) pls[sel * 8 + j][row] = pa[j];
  }
  __syncthreads();                     // only barrier in the kernel

  floatx4 acc[4][7];
#pragma unroll
  for (int sb = 0; sb < 4; sb++)
#pragma unroll
    for (int t = 0; t < 7; t++) acc[sb][t] = (floatx4){0.f, 0.f, 0.f, 0.f};

  // unit u (= ph*32 + i*2 + jj, 0..63): frag index = (split*64 + u)*14 + ntb + t
  const half_t* bp = W1p + ((size_t)split * 64 * 14 + ntb) * 512 + lane * 8;
  const size_t USTRIDE = 14 * 512;     // halfs per unit

  half8 pbA[7], pbB[7];
#pragma unroll
  for (int t = 0; t < 7; t++) pbA[t] = *(const half8*)(bp + t * 512);
  bp += USTRIDE;

  half8 sf[4][2];
#pragma unroll
  for (int ph = 0; ph < 2; ph++) {
#pragma unroll
    for (int sub = 0; sub < 4; sub++) {
      int grow = g0 + wm * 64 + sub * 16 + m;
#pragma unroll
      for (int j2 = 0; j2 < 2; j2++)
        sf[sub][j2] = *(const half8*)(S16 + (size_t)grow * 128 + ph * 64 + j2 * 32 + kc);
    }
#pragma unroll
    for (int i = 0; i < 16; i++) {
      const int s = ph * 16 + i;       // compile-time (both loops unrolled)
      half_t p0 = pls[i][wm * 64 + 0 * 16 + m];
      half_t p1 = pls[i][wm * 64 + 1 * 16 + m];
      half_t p2 = pls[i][wm * 64 + 2 * 16 + m];
      half_t p3 = pls[i][wm * 64 + 3 * 16 + m];
      // jj=0: prefetch next unit into pbB, compute with pbA
#pragma unroll
      for (int t = 0; t < 7; t++) pbB[t] = *(const half8*)(bp + t * 512);
      bp += USTRIDE;
      {
        half8 a0 = sf[0][0] * p0;
        half8 a1 = sf[1][0] * p1;
        half8 a2 = sf[2][0] * p2;
        half8 a3 = sf[3][0] * p3;
#pragma unroll
        for (int t = 0; t < 7; t++) {
          acc[0][t] = mfma16(a0, pbA[t], acc[0][t]);
          acc[1][t] = mfma16(a1, pbA[t], acc[1][t]);
          acc[2][t] = mfma16(a2, pbA[t], acc[2][t]);
          acc[3][t] = mfma16(a3, pbA[t], acc[3][t]);
        }
      }
      // jj=1: prefetch next unit into pbA (unless last step), compute with pbB
      if (s < 31) {
#pragma unroll
        for (int t = 0; t < 7; t++) pbA[t] = *(const half8*)(bp + t * 512);
        bp += USTRIDE;
      }
      {
        half8 a0 = sf[0][1] * p0;
        half8 a1 = sf[1][1] * p1;
        half8 a2 = sf[2][1] * p2;
        half8 a3 = sf[3][1] * p3;
#pragma unroll
        for (int t = 0; t < 7; t++) {
          acc[0][t] = mfma16(a0, pbB[t], acc[0][t]);
          acc[1][t] = mfma16(a1, pbB[t], acc[1][t]);
          acc[2][t] = mfma16(a2, pbB[t], acc[2][t]);
          acc[3][t] = mfma16(a3, pbB[t], acc[3][t]);
        }
      }
    }
  }

  // inline direct stores (store pattern proven traffic-neutral; round-5 layout)
#pragma unroll
  for (int sub = 0; sub < 4; sub++)
#pragma unroll
    for (int t = 0; t < 7; t++)
#pragma unroll
      for (int r = 0; r < 4; r++) {
        int row = g0 + wm * 64 + sub * 16 + q * 4 + r;
        zpart[((size_t)split * GG + row) * NPAD + (ntb + t) * 16 + m] = acc[sub][t][r];
      }
}

// ---------------- split-K reduce + b1 + relu + (200->2) GEMM + b2 ----------------
__global__ __launch_bounds__(256) void reduce_mlp(const float* __restrict__ zpart,
                                                  const float* __restrict__ b1,
                                                  const float* __restrict__ W2,
                                                  const float* __restrict__ b2,
                                                  float* __restrict__ out) {
  int tid = threadIdx.x;
  int w = tid >> 6, lane = tid & 63;
  int g = blockIdx.x * 4 + w;
  float p0 = 0.f, p1 = 0.f;
#pragma unroll
  for (int qq = 0; qq < 4; qq++) {
    int c = qq * 64 + lane;
    if (c < 200) {
      float z = 0.f;
#pragma unroll
      for (int sp = 0; sp < NSPLIT; sp++)
        z += zpart[((size_t)sp * GG + g) * NPAD + c];
      z += b1[c];
      z = fmaxf(z, 0.f);
      p0 += z * W2[c * 2];
      p1 += z * W2[c * 2 + 1];
    }
  }
#pragma unroll
  for (int off = 32; off; off >>= 1) {
    p0 += __shfl_down(p0, off);
    p1 += __shfl_down(p1, off);
  }
  if (lane == 0) {
    out[g * 2] = p0 + b2[0];
    out[g * 2 + 1] = p1 + b2[1];
  }
}

extern "C" void kernel_launch(void* const* d_in, const int* in_sizes, int n_in,
                              void* d_out, int out_size, void* d_ws, size_t ws_size,
                              hipStream_t stream) {
  const float* x     = (const float*)d_in[0];
  const int*   ei    = (const int*)d_in[1];
  const int*   setix = (const int*)d_in[2];
  const float* ir    = (const float*)d_in[4];
  const float* W_l   = (const float*)d_in[5];
  const float* b_l   = (const float*)d_in[6];
  const float* W_r   = (const float*)d_in[7];
  const float* W_ir  = (const float*)d_in[8];
  const float* b_ir  = (const float*)d_in[9];
  const float* W1    = (const float*)d_in[10];
  const float* b1    = (const float*)d_in[11];
  const float* W2    = (const float*)d_in[12];
  const float* b2    = (const float*)d_in[13];
  float* out = (float*)d_out;

  char* ws = (char*)d_ws;
  size_t off = 0;
  auto alloc = [&](size_t bytes) -> void* {
    void* p = ws + off;
    off = (off + bytes + 255) & ~(size_t)255;
    return p;
  };
  // ---- pool: everything here is dead before biggemm; zpart aliases it ----
  size_t pool_start = off;
  int* nodemap   = (int*)alloc((size_t)NN * 4);                       // 512 KB
  int* slot_node = (int*)alloc((size_t)NSEL * 4);                     // 64 KB
  int* scnt      = (int*)alloc((size_t)SBUCK * SUBC * 16 * 4);        // 64 KB (padded counters)
  unsigned int* sbuf = (unsigned int*)alloc((size_t)SBUCK * SUBC * SCAPS * 4); // 1.38 MB
  half_t* y16    = (half_t*)alloc((size_t)NN * 64 * 2);               // 16 MB
  half_t* r_slot = (half_t*)alloc((size_t)NSEL * 64 * 2);             // 2 MB
  half_t* h_slot = (half_t*)alloc((size_t)NSEL * 64 * 2);             // 2 MB
  float* zpart = (float*)(ws + pool_start);
  {  // ensure zpart (58.7 MB) fits inside the dead pool region
    size_t zend = pool_start + (((size_t)NSPLIT * GG * NPAD * 4 + 255) & ~(size_t)255);
    if (off < zend) off = zend;
  }
  // ---- live through biggemm ----
  half_t* Wt     = (half_t*)alloc(128 * 128 * 2);
  half_t* W1p    = (half_t*)alloc((size_t)NPAD * KBIG * 2);
  half_t* S16    = (half_t*)alloc((size_t)GG * 128 * 2);
  half_t* pair16 = (half_t*)alloc((size_t)GG * 128 * 2);
  (void)ws_size; (void)in_sizes; (void)n_in; (void)out_size;

  const int* esrc = ei;
  const int* edst = ei + EE;

  hipMemsetAsync(nodemap, 0xFF, (size_t)NN * 4, stream);   // -1
  hipMemsetAsync(scnt, 0, (size_t)SBUCK * SUBC * 16 * 4, stream);

  prep_w<<<(128 * 128) / 256, 256, 0, stream>>>(W_l, W_r, Wt);
  prep_w1p<<<(NPAD * KBIG / 8) / 256, 256, 0, stream>>>(W1, W1p);

  set_slots<<<NSEL / 256, 256, 0, stream>>>(setix, nodemap, slot_node);
  filter_scatter<<<EE / 256, 256, 0, stream>>>(esrc, edst, nodemap, scnt, sbuf);

  y_gemm<<<NN / 64, 256, 0, stream>>>(x, Wt, y16);
  r_slots<<<NSEL / 64, 256, 0, stream>>>(x, Wt, b_l, slot_node, r_slot);
  slot_agg<<<SBUCK, 256, 0, stream>>>(sbuf, scnt, y16, r_slot, h_slot);

  s_pair_kernel<<<(GG * 128) / 256, 256, 0, stream>>>(ir, W_ir, b_ir, S16, h_slot, nodemap, setix, pair16);

  biggemm<<<(GG / 128) * NSPLIT, 256, 0, stream>>>(pair16, S16, W1p, zpart);
  reduce_mlp<<<GG / 4, 256, 0, stream>>>(zpart, b1, W2, b2, out);
}

// Round 7
// 263.737 us; speedup vs baseline: 1.2508x; 1.2508x over previous
//
#include <hip/hip_runtime.h>

#define NN   131072      // nodes
#define GG   8192        // graphs
#define EE   2097152     // edges
#define KBIG 16384       // (2*GS)^2
#define NPAD 224         // 200 padded to 14*16 (2 waves x 7 nt)
#define NSPLIT 8
#define NSEL  16384      // selected slots (2 per graph)
#define SBUCK 256        // slot buckets of 64 slots
#define SUBC  4          // sub-counters per bucket (atomic spread)
#define SCAPS 336        // per-sub capacity (mean ~237 + 6.4 sigma)
#define SCAPT (SUBC*SCAPS)  // 1344 per bucket

typedef _Float16 half_t;
typedef __attribute__((ext_vector_type(8))) _Float16 half8;
typedef __attribute__((ext_vector_type(4))) float floatx4;

__device__ inline floatx4 mfma16(half8 a, half8 b, floatx4 c) {
  return __builtin_amdgcn_mfma_f32_16x16x32_f16(a, b, c, 0, 0, 0);
}

// ---------------- prep kernels ----------------
// Wt[n][k] (n-major, f16): n<64 -> W_l[k][n], n>=64 -> W_r[k][n-64]
__global__ void prep_w(const float* __restrict__ Wl, const float* __restrict__ Wr,
                       half_t* __restrict__ Wt) {
  int idx = blockIdx.x * blockDim.x + threadIdx.x; // 128*128
  int n = idx >> 7, k = idx & 127;
  float v = (n < 64) ? Wl[k * 64 + n] : Wr[k * 64 + (n - 64)];
  Wt[n * 128 + k] = (half_t)v;
}
// W1p packed fragment-order for phase-split K:
// frag = (((split*2+ph)*16 + i)*2 + jj)*14 + nt ; within frag: lane, 8 elems
// k = split*2048 + i*128 + ph*64 + jj*32 + (lane>>4)*8 + e ; n = nt*16 + (lane&15)
__global__ void prep_w1p(const float* __restrict__ W1, half_t* __restrict__ W1p) {
  int idx = blockIdx.x * blockDim.x + threadIdx.x; // 8*2*16*2*14*64 = 458752
  int lane = idx & 63;
  int t = idx >> 6;
  int nt = t % 14; t /= 14;
  int jj = t & 1;  t >>= 1;
  int i  = t & 15; t >>= 4;
  int ph = t & 1;  t >>= 1;
  int split = t;
  int n = nt * 16 + (lane & 15);
  int k0 = split * 2048 + i * 128 + ph * 64 + jj * 32 + (lane >> 4) * 8;
  half8 v;
#pragma unroll
  for (int e = 0; e < 8; e++)
    v[e] = (half_t)((n < 200) ? W1[(size_t)(k0 + e) * 200 + n] : 0.f);
  *(half8*)(W1p + (size_t)idx * 8) = v;
}

// ---------------- selected-node slot map ----------------
__global__ void set_slots(const int* __restrict__ set_idx, int* __restrict__ nodemap,
                          int* __restrict__ slot_node) {
  int idx = blockIdx.x * blockDim.x + threadIdx.x;   // 16384
  int g = idx >> 1, which = idx & 1;
  int node = g * 16 + set_idx[g * 2 + which];
  slot_node[idx] = node;
  nodemap[node] = idx;
}

// ---------------- filtered edge scatter (only edges into selected nodes) ----------------
__global__ void filter_scatter(const int* __restrict__ src, const int* __restrict__ dst,
                               const int* __restrict__ nodemap,
                               int* __restrict__ scnt, unsigned int* __restrict__ sbuf) {
  int e = blockIdx.x * blockDim.x + threadIdx.x;
  int d = dst[e];
  int slot = nodemap[d];
  if (slot >= 0) {
    int b = slot >> 6;
    int sub = blockIdx.x & (SUBC - 1);
    int pos = atomicAdd(&scnt[(b * SUBC + sub) * 16], 1);
    if (pos < SCAPS)
      sbuf[(size_t)(b * SUBC + sub) * SCAPS + pos] =
          (unsigned int)src[e] | ((unsigned int)(slot & 63) << 17);
  }
}

// ---------------- y = x@W_l only (r is computed per-slot in r_slots) ----------------
__global__ __launch_bounds__(256) void y_gemm(const float* __restrict__ x,
                                              const half_t* __restrict__ WtG,
                                              half_t* __restrict__ y16) {
  __shared__ half_t wlds[64 * 128];   // W_l rows 0..63, 16 KB
  __shared__ half_t ybuf[64 * 72];    // transpose buffer, stride 72 (16B-aligned rows)
  int tid = threadIdx.x, w = tid >> 6, lane = tid & 63;
  int m = lane & 15, q = lane >> 4, kc = q * 8;
#pragma unroll
  for (int it = 0; it < 4; it++) {
    int cb = (it * 4 + w) * 64;       // chunk base for this wave
    const half_t* g = WtG + ((size_t)cb + lane) * 8;
    half_t* l = wlds + (size_t)cb * 8;
    __builtin_amdgcn_global_load_lds((const __attribute__((address_space(1))) uint32_t*)g,
                                     (__attribute__((address_space(3))) uint32_t*)l, 16, 0, 0);
  }
  int node0 = blockIdx.x * 64 + w * 16;
  float4 xu[4][2];
#pragma unroll
  for (int step = 0; step < 4; step++) {
    const float* xp = x + (size_t)(node0 + m) * 128 + step * 32 + kc;
    xu[step][0] = *(const float4*)xp;
    xu[step][1] = *(const float4*)(xp + 4);
  }
  __syncthreads();                    // wlds ready (barrier drains vmcnt)
  floatx4 acc[4];
#pragma unroll
  for (int nt = 0; nt < 4; nt++) acc[nt] = (floatx4){0.f, 0.f, 0.f, 0.f};
#pragma unroll
  for (int step = 0; step < 4; step++) {
    float4 u0 = xu[step][0], u1 = xu[step][1];
    half8 av = {(half_t)u0.x, (half_t)u0.y, (half_t)u0.z, (half_t)u0.w,
                (half_t)u1.x, (half_t)u1.y, (half_t)u1.z, (half_t)u1.w};
    int k0 = step * 32 + kc;
#pragma unroll
    for (int nt = 0; nt < 4; nt++) {
      half8 bv = *(const half8*)(wlds + (nt * 16 + m) * 128 + k0);
      acc[nt] = mfma16(av, bv, acc[nt]);
    }
  }
#pragma unroll
  for (int nt = 0; nt < 4; nt++)
#pragma unroll
    for (int r = 0; r < 4; r++)
      ybuf[(w * 16 + q * 4 + r) * 72 + nt * 16 + m] = (half_t)acc[nt][r];
  __syncthreads();
#pragma unroll
  for (int c = tid; c < 512; c += 256) {
    int row = c >> 3, co = (c & 7) * 8;
    *(half8*)(y16 + (size_t)(blockIdx.x * 64 + row) * 64 + co) =
        *(const half8*)(ybuf + row * 72 + co);
  }
}

// ---------------- r_slot[slot] = x[slot_node[slot]] @ W_r + b_l (16384 slots only) ----------------
__global__ __launch_bounds__(256) void r_slots(const float* __restrict__ x,
                                               const half_t* __restrict__ WtG,
                                               const float* __restrict__ b_l,
                                               const int* __restrict__ slot_node,
                                               half_t* __restrict__ r_slot) {
  int tid = threadIdx.x, w = tid >> 6, lane = tid & 63;
  int m = lane & 15, q = lane >> 4, kc = q * 8;
  int s0 = blockIdx.x * 64 + w * 16;   // 16 slots per wave
  int node = slot_node[s0 + m];
  floatx4 acc[4];
#pragma unroll
  for (int nt = 0; nt < 4; nt++) acc[nt] = (floatx4){0.f, 0.f, 0.f, 0.f};
#pragma unroll
  for (int step = 0; step < 4; step++) {
    int k0 = step * 32 + kc;
    const float* xp = x + (size_t)node * 128 + k0;
    float4 u0 = *(const float4*)xp;
    float4 u1 = *(const float4*)(xp + 4);
    half8 av = {(half_t)u0.x, (half_t)u0.y, (half_t)u0.z, (half_t)u0.w,
                (half_t)u1.x, (half_t)u1.y, (half_t)u1.z, (half_t)u1.w};
#pragma unroll
    for (int nt = 0; nt < 4; nt++) {
      half8 bv = *(const half8*)(WtG + (size_t)(64 + nt * 16 + m) * 128 + k0);
      acc[nt] = mfma16(av, bv, acc[nt]);
    }
  }
#pragma unroll
  for (int nt = 0; nt < 4; nt++) {
    int n = nt * 16 + m;
    float bias = b_l[n];
#pragma unroll
    for (int r = 0; r < 4; r++) {
      int s = s0 + q * 4 + r;
      r_slot[(size_t)s * 64 + n] = (half_t)(acc[nt][r] + bias);
    }
  }
}

// ---------------- per-slot SAGE agg: LDS counting sort + register accumulation ----------------
__global__ __launch_bounds__(256) void slot_agg(const unsigned int* __restrict__ sbuf,
                                                const int* __restrict__ scnt,
                                                const half_t* __restrict__ y16,
                                                const half_t* __restrict__ r_slot,
                                                half_t* __restrict__ h_slot) {
  __shared__ int sorted[SCAPT];    // src indices, grouped by local slot
  __shared__ int hist[64];
  __shared__ int base[64];
  __shared__ int start[65];
  int b = blockIdx.x, tid = threadIdx.x;
  if (tid < 64) hist[tid] = 0;
  __syncthreads();
  unsigned int myedge[2 * SUBC];
  int mycnt = 0;
#pragma unroll
  for (int sub = 0; sub < SUBC; sub++) {
    int n = scnt[(b * SUBC + sub) * 16]; if (n > SCAPS) n = SCAPS;
    const unsigned int* eb = sbuf + (size_t)(b * SUBC + sub) * SCAPS;
    for (int e = tid; e < n; e += 256) {
      unsigned int pk = eb[e];
      myedge[mycnt++] = pk;
      atomicAdd(&hist[pk >> 17], 1);
    }
  }
  __syncthreads();
  if (tid < 64) {                       // wave 0: exclusive scan of 64 bins
    int v = hist[tid];
    int sum = v;
#pragma unroll
    for (int off = 1; off < 64; off <<= 1) {
      int u = __shfl_up(sum, off);
      if (tid >= off) sum += u;
    }
    start[tid] = sum - v;
    base[tid]  = sum - v;
    if (tid == 63) start[64] = sum;
  }
  __syncthreads();
  for (int i = 0; i < mycnt; i++) {
    unsigned int pk = myedge[i];
    int pos = atomicAdd(&base[pk >> 17], 1);
    sorted[pos] = (int)(pk & 0x1FFFF);
  }
  __syncthreads();
  int s = tid >> 2, p = tid & 3;
  int e0 = start[s], e1 = start[s + 1];
  float acc[16];
#pragma unroll
  for (int j = 0; j < 16; j++) acc[j] = 0.f;
  int e = e0;
  for (; e + 2 <= e1; e += 2) {
    int s0 = sorted[e], s1 = sorted[e + 1];
    const half8* p0 = (const half8*)(y16 + (size_t)s0 * 64 + p * 16);
    const half8* p1 = (const half8*)(y16 + (size_t)s1 * 64 + p * 16);
    half8 a0 = p0[0], c0 = p0[1], a1 = p1[0], c1 = p1[1];
#pragma unroll
    for (int j = 0; j < 8; j++) {
      acc[j]     += (float)a0[j] + (float)a1[j];
      acc[8 + j] += (float)c0[j] + (float)c1[j];
    }
  }
  if (e < e1) {
    int s0 = sorted[e];
    const half8* p0 = (const half8*)(y16 + (size_t)s0 * 64 + p * 16);
    half8 a0 = p0[0], c0 = p0[1];
#pragma unroll
    for (int j = 0; j < 8; j++) { acc[j] += (float)a0[j]; acc[8 + j] += (float)c0[j]; }
  }
  int slot = b * 64 + s;
  float inv = 1.0f / fmaxf((float)(e1 - e0), 1.0f);
  const half8* rr = (const half8*)(r_slot + (size_t)slot * 64 + p * 16);
  half8 r0 = rr[0], r1 = rr[1];
  half8 o0, o1;
#pragma unroll
  for (int j = 0; j < 8; j++) {
    o0[j] = (half_t)fmaxf(acc[j] * inv + (float)r0[j], 0.f);
    o1[j] = (half_t)fmaxf(acc[8 + j] * inv + (float)r1[j], 0.f);
  }
  half8* hp = (half8*)(h_slot + (size_t)slot * 64 + p * 16);
  hp[0] = o0;
  hp[1] = o1;
}

// ---------------- S = relu(ir @ W_ir + b_ir) and pair gather from h_slot ----------------
__global__ void s_pair_kernel(const float* __restrict__ ir, const float* __restrict__ W_ir,
                              const float* __restrict__ b_ir, half_t* __restrict__ S16,
                              const half_t* __restrict__ h_slot,
                              const int* __restrict__ nodemap,
                              const int* __restrict__ set_idx, half_t* __restrict__ pair16) {
  int idx = blockIdx.x * blockDim.x + threadIdx.x; // G*128
  int g = idx >> 7, o = idx & 127;
  const float* irow = ir + g * 32;
  float sv = b_ir[o];
#pragma unroll
  for (int a = 0; a < 32; a++) sv += irow[a] * W_ir[a * 128 + o];
  S16[idx] = (half_t)fmaxf(sv, 0.f);
  int which = o >> 6, c = o & 63;
  int node = g * 16 + set_idx[g * 2 + which];
  int slot = nodemap[node];
  pair16[idx] = h_slot[(size_t)slot * 64 + c];
}

// ---------------- z-partials: (pair(x)S) @ W1, split-K=8, BM=128 ----------------
// Round-5 compute (2x2 wave grid, reuse-4, sf[4][2] phase-split, no spill) with the
// sync fabric replaced by T3/T4 counted-vmcnt pipelining (m201 pattern): 2 stage-units
// in flight, per-step `s_waitcnt vmcnt(7)` (= my oldest 7 DMA loads done, never 0) +
// raw s_barrier; second raw barrier before re-staging the freed buffer. Removes the
// 32x full vmcnt(0) drains that __syncthreads emitted (round-6 proved the wall is the
// sync fabric, not LDS/MFMA/L2 pipes: all <40% busy).
__global__ __launch_bounds__(256, 2) void biggemm(const half_t* __restrict__ pair16,
                                                  const half_t* __restrict__ S16,
                                                  const half_t* __restrict__ W1p,
                                                  float* __restrict__ zpart) {
  __shared__ __align__(16) half_t bbuf[2][28 * 512];   // 57344 B, 2 step-units
  __shared__ half_t pls[16][128];                      // 4096 B
  int bx = blockIdx.x;
  int mt = bx >> 3, split = bx & 7;   // split == XCD id -> W1 slice L2-resident per XCD
  int g0 = mt * 128;
  int tid = threadIdx.x, w = tid >> 6, lane = tid & 63;
  int wm = w >> 1, wn = w & 1;        // 2x2 wave grid
  int m = lane & 15, q = lane >> 4, kc = q * 8;
  int ntb = wn * 7;                   // this wave's nt base (7 nt groups)

  // stage all 28 frags of step-unit s (= ph*16+i) into bbuf[buf]; 7 loads per wave
  auto stage = [&](int s, int buf) {
#pragma unroll
    for (int ff = 0; ff < 7; ff++) {
      int f = ff * 4 + w;             // 28 = 7 x 4 waves
      const half_t* gsrc = W1p + (((size_t)(split * 32 + s) * 28) + f) * 512 + lane * 8;
      half_t* ldst = &bbuf[buf][f * 512];
      __builtin_amdgcn_global_load_lds((const __attribute__((address_space(1))) uint32_t*)gsrc,
                                       (__attribute__((address_space(3))) uint32_t*)ldst, 16, 0, 0);
    }
  };

  {
    int row = tid & 127, sel = tid >> 7;
    half8 pa = *(const half8*)(pair16 + (size_t)(g0 + row) * 128 + split * 16 + sel * 8);
#pragma unroll
    for (int j = 0; j < 8; j++) pls[sel * 8 + j][row] = pa[j];
  }
  __syncthreads();                     // pls visible (full drain, one-time prologue cost)

  stage(0, 0);                         // 7 outstanding
  stage(1, 1);                         // 14 outstanding

  floatx4 acc[4][7];
#pragma unroll
  for (int sb = 0; sb < 4; sb++)
#pragma unroll
    for (int t = 0; t < 7; t++) acc[sb][t] = (floatx4){0.f, 0.f, 0.f, 0.f};

  half8 sf[4][2];   // only current phase's S-fragment block lives in registers
#pragma unroll
  for (int ph = 0; ph < 2; ph++) {
#pragma unroll
    for (int sub = 0; sub < 4; sub++) {
      int grow = g0 + wm * 64 + sub * 16 + m;
#pragma unroll
      for (int j2 = 0; j2 < 2; j2++)
        sf[sub][j2] = *(const half8*)(S16 + (size_t)grow * 128 + ph * 64 + j2 * 32 + kc);
    }
#pragma unroll
    for (int i = 0; i < 16; i++) {
      const int s = ph * 16 + i;       // compile-time (both loops unrolled)
      const int cur = s & 1;
      // my stage-s loads done (oldest 7 of <=14): counted wait, never drains pipeline
      if (ph == 1 && i == 15) {
        asm volatile("s_waitcnt vmcnt(0)" ::: "memory");
      } else {
        asm volatile("s_waitcnt vmcnt(7)" ::: "memory");
      }
      __builtin_amdgcn_sched_barrier(0);
      __builtin_amdgcn_s_barrier();    // all waves' stage-s loads complete
      __builtin_amdgcn_sched_barrier(0);

      half_t p0 = pls[i][wm * 64 + 0 * 16 + m];
      half_t p1 = pls[i][wm * 64 + 1 * 16 + m];
      half_t p2 = pls[i][wm * 64 + 2 * 16 + m];
      half_t p3 = pls[i][wm * 64 + 3 * 16 + m];
      const half_t* bb = bbuf[cur];
#pragma unroll
      for (int jj = 0; jj < 2; jj++) {
        half8 a0 = sf[0][jj] * p0;
        half8 a1 = sf[1][jj] * p1;
        half8 a2 = sf[2][jj] * p2;
        half8 a3 = sf[3][jj] * p3;
#pragma unroll
        for (int t = 0; t < 7; t++) {
          half8 bv = *(const half8*)(bb + (jj * 14 + ntb + t) * 512 + lane * 8);
          acc[0][t] = mfma16(a0, bv, acc[0][t]);
          acc[1][t] = mfma16(a1, bv, acc[1][t]);
          acc[2][t] = mfma16(a2, bv, acc[2][t]);
          acc[3][t] = mfma16(a3, bv, acc[3][t]);
        }
      }

      if (s < 30) {
        // all waves finished reading bbuf[cur] (ds_read data is in regs before a wave
        // reaches the barrier) -> safe to re-stage it
        __builtin_amdgcn_sched_barrier(0);
        __builtin_amdgcn_s_barrier();
        __builtin_amdgcn_sched_barrier(0);
        stage(s + 2, cur);             // back to 14 outstanding
      }
    }
  }

  // inline direct stores (store pattern proven traffic-neutral; round-5 layout)
#pragma unroll
  for (int sub = 0; sub < 4; sub++)
#pragma unroll
    for (int t = 0; t < 7; t++)
#pragma unroll
      for (int r = 0; r < 4; r++) {
        int row = g0 + wm * 64 + sub * 16 + q * 4 + r;
        zpart[((size_t)split * GG + row) * NPAD + (ntb + t) * 16 + m] = acc[sub][t][r];
      }
}

// ---------------- split-K reduce + b1 + relu + (200->2) GEMM + b2 ----------------
__global__ __launch_bounds__(256) void reduce_mlp(const float* __restrict__ zpart,
                                                  const float* __restrict__ b1,
                                                  const float* __restrict__ W2,
                                                  const float* __restrict__ b2,
                                                  float* __restrict__ out) {
  int tid = threadIdx.x;
  int w = tid >> 6, lane = tid & 63;
  int g = blockIdx.x * 4 + w;
  float p0 = 0.f, p1 = 0.f;
#pragma unroll
  for (int qq = 0; qq < 4; qq++) {
    int c = qq * 64 + lane;
    if (c < 200) {
      float z = 0.f;
#pragma unroll
      for (int sp = 0; sp < NSPLIT; sp++)
        z += zpart[((size_t)sp * GG + g) * NPAD + c];
      z += b1[c];
      z = fmaxf(z, 0.f);
      p0 += z * W2[c * 2];
      p1 += z * W2[c * 2 + 1];
    }
  }
#pragma unroll
  for (int off = 32; off; off >>= 1) {
    p0 += __shfl_down(p0, off);
    p1 += __shfl_down(p1, off);
  }
  if (lane == 0) {
    out[g * 2] = p0 + b2[0];
    out[g * 2 + 1] = p1 + b2[1];
  }
}

extern "C" void kernel_launch(void* const* d_in, const int* in_sizes, int n_in,
                              void* d_out, int out_size, void* d_ws, size_t ws_size,
                              hipStream_t stream) {
  const float* x     = (const float*)d_in[0];
  const int*   ei    = (const int*)d_in[1];
  const int*   setix = (const int*)d_in[2];
  const float* ir    = (const float*)d_in[4];
  const float* W_l   = (const float*)d_in[5];
  const float* b_l   = (const float*)d_in[6];
  const float* W_r   = (const float*)d_in[7];
  const float* W_ir  = (const float*)d_in[8];
  const float* b_ir  = (const float*)d_in[9];
  const float* W1    = (const float*)d_in[10];
  const float* b1    = (const float*)d_in[11];
  const float* W2    = (const float*)d_in[12];
  const float* b2    = (const float*)d_in[13];
  float* out = (float*)d_out;

  char* ws = (char*)d_ws;
  size_t off = 0;
  auto alloc = [&](size_t bytes) -> void* {
    void* p = ws + off;
    off = (off + bytes + 255) & ~(size_t)255;
    return p;
  };
  // ---- pool: everything here is dead before biggemm; zpart aliases it ----
  size_t pool_start = off;
  int* nodemap   = (int*)alloc((size_t)NN * 4);                       // 512 KB
  int* slot_node = (int*)alloc((size_t)NSEL * 4);                     // 64 KB
  int* scnt      = (int*)alloc((size_t)SBUCK * SUBC * 16 * 4);        // 64 KB (padded counters)
  unsigned int* sbuf = (unsigned int*)alloc((size_t)SBUCK * SUBC * SCAPS * 4); // 1.38 MB
  half_t* y16    = (half_t*)alloc((size_t)NN * 64 * 2);               // 16 MB
  half_t* r_slot = (half_t*)alloc((size_t)NSEL * 64 * 2);             // 2 MB
  half_t* h_slot = (half_t*)alloc((size_t)NSEL * 64 * 2);             // 2 MB
  float* zpart = (float*)(ws + pool_start);
  {  // ensure zpart (58.7 MB) fits inside the dead pool region
    size_t zend = pool_start + (((size_t)NSPLIT * GG * NPAD * 4 + 255) & ~(size_t)255);
    if (off < zend) off = zend;
  }
  // ---- live through biggemm ----
  half_t* Wt     = (half_t*)alloc(128 * 128 * 2);
  half_t* W1p    = (half_t*)alloc((size_t)NPAD * KBIG * 2);
  half_t* S16    = (half_t*)alloc((size_t)GG * 128 * 2);
  half_t* pair16 = (half_t*)alloc((size_t)GG * 128 * 2);
  (void)ws_size; (void)in_sizes; (void)n_in; (void)out_size;

  const int* esrc = ei;
  const int* edst = ei + EE;

  hipMemsetAsync(nodemap, 0xFF, (size_t)NN * 4, stream);   // -1
  hipMemsetAsync(scnt, 0, (size_t)SBUCK * SUBC * 16 * 4, stream);

  prep_w<<<(128 * 128) / 256, 256, 0, stream>>>(W_l, W_r, Wt);
  prep_w1p<<<(NPAD * KBIG / 8) / 256, 256, 0, stream>>>(W1, W1p);

  set_slots<<<NSEL / 256, 256, 0, stream>>>(setix, nodemap, slot_node);
  filter_scatter<<<EE / 256, 256, 0, stream>>>(esrc, edst, nodemap, scnt, sbuf);

  y_gemm<<<NN / 64, 256, 0, stream>>>(x, Wt, y16);
  r_slots<<<NSEL / 64, 256, 0, stream>>>(x, Wt, b_l, slot_node, r_slot);
  slot_agg<<<SBUCK, 256, 0, stream>>>(sbuf, scnt, y16, r_slot, h_slot);

  s_pair_kernel<<<(GG * 128) / 256, 256, 0, stream>>>(ir, W_ir, b_ir, S16, h_slot, nodemap, setix, pair16);

  biggemm<<<(GG / 128) * NSPLIT, 256, 0, stream>>>(pair16, S16, W1p, zpart);
  reduce_mlp<<<GG / 4, 256, 0, stream>>>(zpart, b1, W2, b2, out);
}

// Round 8
// 256.247 us; speedup vs baseline: 1.2873x; 1.0292x over previous
//
#include <hip/hip_runtime.h>

#define NN   131072      // nodes
#define GG   8192        // graphs
#define EE   2097152     // edges
#define KBIG 16384       // (2*GS)^2
#define NPAD 224         // 200 padded to 14*16 (2 waves x 7 nt)
#define NSPLIT 8
#define NSEL  16384      // selected slots (2 per graph)
#define SBUCK 256        // slot buckets of 64 slots
#define SUBC  4          // sub-counters per bucket (atomic spread)
#define SCAPS 336        // per-sub capacity (mean ~237 + 6.4 sigma)
#define SCAPT (SUBC*SCAPS)  // 1344 per bucket

typedef _Float16 half_t;
typedef __attribute__((ext_vector_type(8))) _Float16 half8;
typedef __attribute__((ext_vector_type(4))) float floatx4;

__device__ inline floatx4 mfma16(half8 a, half8 b, floatx4 c) {
  return __builtin_amdgcn_mfma_f32_16x16x32_f16(a, b, c, 0, 0, 0);
}

// ---------------- fused prep: W1p repack | Wt repack | slot_node | scnt zero ----------------
// blocks [0,1792): prep_w1p ; [1792,1856): prep_w ; [1856,1920): slot_node ; [1920,1984): scnt=0
__global__ __launch_bounds__(256) void prep_all(const float* __restrict__ Wl,
                                                const float* __restrict__ Wr,
                                                const float* __restrict__ W1,
                                                const int* __restrict__ setix,
                                                half_t* __restrict__ Wt,
                                                half_t* __restrict__ W1p,
                                                int* __restrict__ slot_node,
                                                int* __restrict__ scnt) {
  int b = blockIdx.x, tid = threadIdx.x;
  if (b < 1792) {
    // W1p packed fragment-order for phase-split K:
    // frag = (((split*2+ph)*16 + i)*2 + jj)*14 + nt ; within frag: lane, 8 elems
    int idx = b * 256 + tid;          // 8*2*16*2*14*64 = 458752
    int lane = idx & 63;
    int t = idx >> 6;
    int nt = t % 14; t /= 14;
    int jj = t & 1;  t >>= 1;
    int i  = t & 15; t >>= 4;
    int ph = t & 1;  t >>= 1;
    int split = t;
    int n = nt * 16 + (lane & 15);
    int k0 = split * 2048 + i * 128 + ph * 64 + jj * 32 + (lane >> 4) * 8;
    half8 v;
#pragma unroll
    for (int e = 0; e < 8; e++)
      v[e] = (half_t)((n < 200) ? W1[(size_t)(k0 + e) * 200 + n] : 0.f);
    *(half8*)(W1p + (size_t)idx * 8) = v;
  } else if (b < 1856) {
    // Wt[n][k] (n-major, f16): n<64 -> W_l[k][n], n>=64 -> W_r[k][n-64]
    int idx = (b - 1792) * 256 + tid; // 128*128
    int n = idx >> 7, k = idx & 127;
    float v = (n < 64) ? Wl[k * 64 + n] : Wr[k * 64 + (n - 64)];
    Wt[n * 128 + k] = (half_t)v;
  } else if (b < 1920) {
    int idx = (b - 1856) * 256 + tid; // 16384 slots
    slot_node[idx] = (idx >> 1) * 16 + setix[idx];
  } else {
    int idx = (b - 1920) * 256 + tid; // 16384 ints (SBUCK*SUBC*16)
    scnt[idx] = 0;
  }
}

// ---------------- fused mid: y_gemm | r_slots | filter_scatter ----------------
// blocks [0,2048): y = x@W_l ; [2048,2304): r_slot ; [2304,10496): edge filter.
// All parts depend only on prep_all outputs; no intra-kernel cross-deps.
// Slot is computed ARITHMETICALLY (si0-priority canonical): no nodemap, no memset,
// no 512KB random gather. s_pair uses the same canonicalization.
__global__ __launch_bounds__(256) void fused_mid(const float* __restrict__ x,
                                                 const half_t* __restrict__ WtG,
                                                 const float* __restrict__ b_l,
                                                 const int* __restrict__ slot_node,
                                                 const int* __restrict__ setix,
                                                 const int* __restrict__ src,
                                                 const int* __restrict__ dst,
                                                 int* __restrict__ scnt,
                                                 unsigned int* __restrict__ sbuf,
                                                 half_t* __restrict__ y16,
                                                 half_t* __restrict__ r_slot) {
  __shared__ half_t wlds[64 * 128];   // y_gemm: W_l rows 0..63, 16 KB
  __shared__ half_t ybuf[64 * 72];    // y_gemm: transpose buffer (stride 72)
  int b = blockIdx.x, tid = threadIdx.x;
  if (b < 2048) {
    int w = tid >> 6, lane = tid & 63;
    int m = lane & 15, q = lane >> 4, kc = q * 8;
#pragma unroll
    for (int it = 0; it < 4; it++) {
      int cb = (it * 4 + w) * 64;
      const half_t* g = WtG + ((size_t)cb + lane) * 8;
      half_t* l = wlds + (size_t)cb * 8;
      __builtin_amdgcn_global_load_lds((const __attribute__((address_space(1))) uint32_t*)g,
                                       (__attribute__((address_space(3))) uint32_t*)l, 16, 0, 0);
    }
    int node0 = b * 64 + w * 16;
    float4 xu[4][2];
#pragma unroll
    for (int step = 0; step < 4; step++) {
      const float* xp = x + (size_t)(node0 + m) * 128 + step * 32 + kc;
      xu[step][0] = *(const float4*)xp;
      xu[step][1] = *(const float4*)(xp + 4);
    }
    __syncthreads();                  // wlds ready
    floatx4 acc[4];
#pragma unroll
    for (int nt = 0; nt < 4; nt++) acc[nt] = (floatx4){0.f, 0.f, 0.f, 0.f};
#pragma unroll
    for (int step = 0; step < 4; step++) {
      float4 u0 = xu[step][0], u1 = xu[step][1];
      half8 av = {(half_t)u0.x, (half_t)u0.y, (half_t)u0.z, (half_t)u0.w,
                  (half_t)u1.x, (half_t)u1.y, (half_t)u1.z, (half_t)u1.w};
      int k0 = step * 32 + kc;
#pragma unroll
      for (int nt = 0; nt < 4; nt++) {
        half8 bv = *(const half8*)(wlds + (nt * 16 + m) * 128 + k0);
        acc[nt] = mfma16(av, bv, acc[nt]);
      }
    }
#pragma unroll
    for (int nt = 0; nt < 4; nt++)
#pragma unroll
      for (int r = 0; r < 4; r++)
        ybuf[(w * 16 + q * 4 + r) * 72 + nt * 16 + m] = (half_t)acc[nt][r];
    __syncthreads();
#pragma unroll
    for (int c = tid; c < 512; c += 256) {
      int row = c >> 3, co = (c & 7) * 8;
      *(half8*)(y16 + (size_t)(b * 64 + row) * 64 + co) =
          *(const half8*)(ybuf + row * 72 + co);
    }
  } else if (b < 2304) {
    // r_slot[slot] = x[slot_node[slot]] @ W_r + b_l (16384 slots)
    int w = tid >> 6, lane = tid & 63;
    int m = lane & 15, q = lane >> 4, kc = q * 8;
    int s0 = (b - 2048) * 64 + w * 16;
    int node = slot_node[s0 + m];
    floatx4 acc[4];
#pragma unroll
    for (int nt = 0; nt < 4; nt++) acc[nt] = (floatx4){0.f, 0.f, 0.f, 0.f};
#pragma unroll
    for (int step = 0; step < 4; step++) {
      int k0 = step * 32 + kc;
      const float* xp = x + (size_t)node * 128 + k0;
      float4 u0 = *(const float4*)xp;
      float4 u1 = *(const float4*)(xp + 4);
      half8 av = {(half_t)u0.x, (half_t)u0.y, (half_t)u0.z, (half_t)u0.w,
                  (half_t)u1.x, (half_t)u1.y, (half_t)u1.z, (half_t)u1.w};
#pragma unroll
      for (int nt = 0; nt < 4; nt++) {
        half8 bv = *(const half8*)(WtG + (size_t)(64 + nt * 16 + m) * 128 + k0);
        acc[nt] = mfma16(av, bv, acc[nt]);
      }
    }
#pragma unroll
    for (int nt = 0; nt < 4; nt++) {
      int n = nt * 16 + m;
      float bias = b_l[n];
#pragma unroll
      for (int r = 0; r < 4; r++) {
        int s = s0 + q * 4 + r;
        r_slot[(size_t)s * 64 + n] = (half_t)(acc[nt][r] + bias);
      }
    }
  } else {
    // filter_scatter, arithmetic slot (si0-priority canonical)
    int eb = b - 2304;
    int e = eb * 256 + tid;
    int d = dst[e];
    int g = d >> 4, local = d & 15;
    int si0 = setix[g * 2], si1 = setix[g * 2 + 1];
    int slot = (local == si0) ? g * 2 : ((local == si1) ? g * 2 + 1 : -1);
    if (slot >= 0) {
      int bk = slot >> 6;
      int sub = eb & (SUBC - 1);
      int pos = atomicAdd(&scnt[(bk * SUBC + sub) * 16], 1);
      if (pos < SCAPS)
        sbuf[(size_t)(bk * SUBC + sub) * SCAPS + pos] =
            (unsigned int)src[e] | ((unsigned int)(slot & 63) << 17);
    }
  }
}

// ---------------- per-slot SAGE agg: LDS counting sort + register accumulation ----------------
__global__ __launch_bounds__(256) void slot_agg(const unsigned int* __restrict__ sbuf,
                                                const int* __restrict__ scnt,
                                                const half_t* __restrict__ y16,
                                                const half_t* __restrict__ r_slot,
                                                half_t* __restrict__ h_slot) {
  __shared__ int sorted[SCAPT];    // src indices, grouped by local slot
  __shared__ int hist[64];
  __shared__ int base[64];
  __shared__ int start[65];
  int b = blockIdx.x, tid = threadIdx.x;
  if (tid < 64) hist[tid] = 0;
  __syncthreads();
  unsigned int myedge[2 * SUBC];
  int mycnt = 0;
#pragma unroll
  for (int sub = 0; sub < SUBC; sub++) {
    int n = scnt[(b * SUBC + sub) * 16]; if (n > SCAPS) n = SCAPS;
    const unsigned int* eb = sbuf + (size_t)(b * SUBC + sub) * SCAPS;
    for (int e = tid; e < n; e += 256) {
      unsigned int pk = eb[e];
      myedge[mycnt++] = pk;
      atomicAdd(&hist[pk >> 17], 1);
    }
  }
  __syncthreads();
  if (tid < 64) {                       // wave 0: exclusive scan of 64 bins
    int v = hist[tid];
    int sum = v;
#pragma unroll
    for (int off = 1; off < 64; off <<= 1) {
      int u = __shfl_up(sum, off);
      if (tid >= off) sum += u;
    }
    start[tid] = sum - v;
    base[tid]  = sum - v;
    if (tid == 63) start[64] = sum;
  }
  __syncthreads();
  for (int i = 0; i < mycnt; i++) {
    unsigned int pk = myedge[i];
    int pos = atomicAdd(&base[pk >> 17], 1);
    sorted[pos] = (int)(pk & 0x1FFFF);
  }
  __syncthreads();
  int s = tid >> 2, p = tid & 3;
  int e0 = start[s], e1 = start[s + 1];
  float acc[16];
#pragma unroll
  for (int j = 0; j < 16; j++) acc[j] = 0.f;
  int e = e0;
  for (; e + 2 <= e1; e += 2) {
    int s0 = sorted[e], s1 = sorted[e + 1];
    const half8* p0 = (const half8*)(y16 + (size_t)s0 * 64 + p * 16);
    const half8* p1 = (const half8*)(y16 + (size_t)s1 * 64 + p * 16);
    half8 a0 = p0[0], c0 = p0[1], a1 = p1[0], c1 = p1[1];
#pragma unroll
    for (int j = 0; j < 8; j++) {
      acc[j]     += (float)a0[j] + (float)a1[j];
      acc[8 + j] += (float)c0[j] + (float)c1[j];
    }
  }
  if (e < e1) {
    int s0 = sorted[e];
    const half8* p0 = (const half8*)(y16 + (size_t)s0 * 64 + p * 16);
    half8 a0 = p0[0], c0 = p0[1];
#pragma unroll
    for (int j = 0; j < 8; j++) { acc[j] += (float)a0[j]; acc[8 + j] += (float)c0[j]; }
  }
  int slot = b * 64 + s;
  float inv = 1.0f / fmaxf((float)(e1 - e0), 1.0f);
  const half8* rr = (const half8*)(r_slot + (size_t)slot * 64 + p * 16);
  half8 r0 = rr[0], r1 = rr[1];
  half8 o0, o1;
#pragma unroll
  for (int j = 0; j < 8; j++) {
    o0[j] = (half_t)fmaxf(acc[j] * inv + (float)r0[j], 0.f);
    o1[j] = (half_t)fmaxf(acc[8 + j] * inv + (float)r1[j], 0.f);
  }
  half8* hp = (half8*)(h_slot + (size_t)slot * 64 + p * 16);
  hp[0] = o0;
  hp[1] = o1;
}

// ---------------- S = relu(ir @ W_ir + b_ir) and pair gather from h_slot ----------------
__global__ void s_pair_kernel(const float* __restrict__ ir, const float* __restrict__ W_ir,
                              const float* __restrict__ b_ir, half_t* __restrict__ S16,
                              const half_t* __restrict__ h_slot,
                              const int* __restrict__ set_idx, half_t* __restrict__ pair16) {
  int idx = blockIdx.x * blockDim.x + threadIdx.x; // G*128
  int g = idx >> 7, o = idx & 127;
  const float* irow = ir + g * 32;
  float sv = b_ir[o];
#pragma unroll
  for (int a = 0; a < 32; a++) sv += irow[a] * W_ir[a * 128 + o];
  S16[idx] = (half_t)fmaxf(sv, 0.f);
  int which = o >> 6, c = o & 63;
  int li = set_idx[g * 2 + which];
  // same si0-priority canonical slot as filter_scatter
  int slot = (li == set_idx[g * 2]) ? g * 2 : g * 2 + 1;
  pair16[idx] = h_slot[(size_t)slot * 64 + c];
}

// ---------------- z-partials: (pair(x)S) @ W1, split-K=8, BM=128 ----------------
// Round-7 version (kept byte-identical for attribution): 2x2 wave grid, reuse-4,
// sf[4][2] phase-split, counted-vmcnt T3/T4 pipelining, 2 stage-units in flight.
__global__ __launch_bounds__(256, 2) void biggemm(const half_t* __restrict__ pair16,
                                                  const half_t* __restrict__ S16,
                                                  const half_t* __restrict__ W1p,
                                                  float* __restrict__ zpart) {
  __shared__ __align__(16) half_t bbuf[2][28 * 512];   // 57344 B, 2 step-units
  __shared__ half_t pls[16][128];                      // 4096 B
  int bx = blockIdx.x;
  int mt = bx >> 3, split = bx & 7;   // split == XCD id -> W1 slice L2-resident per XCD
  int g0 = mt * 128;
  int tid = threadIdx.x, w = tid >> 6, lane = tid & 63;
  int wm = w >> 1, wn = w & 1;        // 2x2 wave grid
  int m = lane & 15, q = lane >> 4, kc = q * 8;
  int ntb = wn * 7;                   // this wave's nt base (7 nt groups)

  auto stage = [&](int s, int buf) {
#pragma unroll
    for (int ff = 0; ff < 7; ff++) {
      int f = ff * 4 + w;             // 28 = 7 x 4 waves
      const half_t* gsrc = W1p + (((size_t)(split * 32 + s) * 28) + f) * 512 + lane * 8;
      half_t* ldst = &bbuf[buf][f * 512];
      __builtin_amdgcn_global_load_lds((const __attribute__((address_space(1))) uint32_t*)gsrc,
                                       (__attribute__((address_space(3))) uint32_t*)ldst, 16, 0, 0);
    }
  };

  {
    int row = tid & 127, sel = tid >> 7;
    half8 pa = *(const half8*)(pair16 + (size_t)(g0 + row) * 128 + split * 16 + sel * 8);
#pragma unroll
    for (int j = 0; j < 8; j++) pls[sel * 8 + j][row] = pa[j];
  }
  __syncthreads();                     // pls visible (one-time prologue drain)

  stage(0, 0);                         // 7 outstanding
  stage(1, 1);                         // 14 outstanding

  floatx4 acc[4][7];
#pragma unroll
  for (int sb = 0; sb < 4; sb++)
#pragma unroll
    for (int t = 0; t < 7; t++) acc[sb][t] = (floatx4){0.f, 0.f, 0.f, 0.f};

  half8 sf[4][2];   // only current phase's S-fragment block lives in registers
#pragma unroll
  for (int ph = 0; ph < 2; ph++) {
#pragma unroll
    for (int sub = 0; sub < 4; sub++) {
      int grow = g0 + wm * 64 + sub * 16 + m;
#pragma unroll
      for (int j2 = 0; j2 < 2; j2++)
        sf[sub][j2] = *(const half8*)(S16 + (size_t)grow * 128 + ph * 64 + j2 * 32 + kc);
    }
#pragma unroll
    for (int i = 0; i < 16; i++) {
      const int s = ph * 16 + i;
      const int cur = s & 1;
      if (ph == 1 && i == 15) {
        asm volatile("s_waitcnt vmcnt(0)" ::: "memory");
      } else {
        asm volatile("s_waitcnt vmcnt(7)" ::: "memory");
      }
      __builtin_amdgcn_sched_barrier(0);
      __builtin_amdgcn_s_barrier();    // all waves' stage-s loads complete
      __builtin_amdgcn_sched_barrier(0);

      half_t p0 = pls[i][wm * 64 + 0 * 16 + m];
      half_t p1 = pls[i][wm * 64 + 1 * 16 + m];
      half_t p2 = pls[i][wm * 64 + 2 * 16 + m];
      half_t p3 = pls[i][wm * 64 + 3 * 16 + m];
      const half_t* bb = bbuf[cur];
#pragma unroll
      for (int jj = 0; jj < 2; jj++) {
        half8 a0 = sf[0][jj] * p0;
        half8 a1 = sf[1][jj] * p1;
        half8 a2 = sf[2][jj] * p2;
        half8 a3 = sf[3][jj] * p3;
#pragma unroll
        for (int t = 0; t < 7; t++) {
          half8 bv = *(const half8*)(bb + (jj * 14 + ntb + t) * 512 + lane * 8);
          acc[0][t] = mfma16(a0, bv, acc[0][t]);
          acc[1][t] = mfma16(a1, bv, acc[1][t]);
          acc[2][t] = mfma16(a2, bv, acc[2][t]);
          acc[3][t] = mfma16(a3, bv, acc[3][t]);
        }
      }

      if (s < 30) {
        __builtin_amdgcn_sched_barrier(0);
        __builtin_amdgcn_s_barrier();
        __builtin_amdgcn_sched_barrier(0);
        stage(s + 2, cur);             // back to 14 outstanding
      }
    }
  }

#pragma unroll
  for (int sub = 0; sub < 4; sub++)
#pragma unroll
    for (int t = 0; t < 7; t++)
#pragma unroll
      for (int r = 0; r < 4; r++) {
        int row = g0 + wm * 64 + sub * 16 + q * 4 + r;
        zpart[((size_t)split * GG + row) * NPAD + (ntb + t) * 16 + m] = acc[sub][t][r];
      }
}

// ---------------- split-K reduce + b1 + relu + (200->2) GEMM + b2 ----------------
__global__ __launch_bounds__(256) void reduce_mlp(const float* __restrict__ zpart,
                                                  const float* __restrict__ b1,
                                                  const float* __restrict__ W2,
                                                  const float* __restrict__ b2,
                                                  float* __restrict__ out) {
  int tid = threadIdx.x;
  int w = tid >> 6, lane = tid & 63;
  int g = blockIdx.x * 4 + w;
  float p0 = 0.f, p1 = 0.f;
#pragma unroll
  for (int qq = 0; qq < 4; qq++) {
    int c = qq * 64 + lane;
    if (c < 200) {
      float z = 0.f;
#pragma unroll
      for (int sp = 0; sp < NSPLIT; sp++)
        z += zpart[((size_t)sp * GG + g) * NPAD + c];
      z += b1[c];
      z = fmaxf(z, 0.f);
      p0 += z * W2[c * 2];
      p1 += z * W2[c * 2 + 1];
    }
  }
#pragma unroll
  for (int off = 32; off; off >>= 1) {
    p0 += __shfl_down(p0, off);
    p1 += __shfl_down(p1, off);
  }
  if (lane == 0) {
    out[g * 2] = p0 + b2[0];
    out[g * 2 + 1] = p1 + b2[1];
  }
}

extern "C" void kernel_launch(void* const* d_in, const int* in_sizes, int n_in,
                              void* d_out, int out_size, void* d_ws, size_t ws_size,
                              hipStream_t stream) {
  const float* x     = (const float*)d_in[0];
  const int*   ei    = (const int*)d_in[1];
  const int*   setix = (const int*)d_in[2];
  const float* ir    = (const float*)d_in[4];
  const float* W_l   = (const float*)d_in[5];
  const float* b_l   = (const float*)d_in[6];
  const float* W_r   = (const float*)d_in[7];
  const float* W_ir  = (const float*)d_in[8];
  const float* b_ir  = (const float*)d_in[9];
  const float* W1    = (const float*)d_in[10];
  const float* b1    = (const float*)d_in[11];
  const float* W2    = (const float*)d_in[12];
  const float* b2    = (const float*)d_in[13];
  float* out = (float*)d_out;

  char* ws = (char*)d_ws;
  size_t off = 0;
  auto alloc = [&](size_t bytes) -> void* {
    void* p = ws + off;
    off = (off + bytes + 255) & ~(size_t)255;
    return p;
  };
  // ---- pool: everything here is dead before biggemm; zpart aliases it ----
  size_t pool_start = off;
  int* slot_node = (int*)alloc((size_t)NSEL * 4);                     // 64 KB
  int* scnt      = (int*)alloc((size_t)SBUCK * SUBC * 16 * 4);        // 64 KB (padded counters)
  unsigned int* sbuf = (unsigned int*)alloc((size_t)SBUCK * SUBC * SCAPS * 4); // 1.38 MB
  half_t* y16    = (half_t*)alloc((size_t)NN * 64 * 2);               // 16 MB
  half_t* r_slot = (half_t*)alloc((size_t)NSEL * 64 * 2);             // 2 MB
  half_t* h_slot = (half_t*)alloc((size_t)NSEL * 64 * 2);             // 2 MB
  float* zpart = (float*)(ws + pool_start);
  {  // ensure zpart (58.7 MB) fits inside the dead pool region
    size_t zend = pool_start + (((size_t)NSPLIT * GG * NPAD * 4 + 255) & ~(size_t)255);
    if (off < zend) off = zend;
  }
  // ---- live through biggemm ----
  half_t* Wt     = (half_t*)alloc(128 * 128 * 2);
  half_t* W1p    = (half_t*)alloc((size_t)NPAD * KBIG * 2);
  half_t* S16    = (half_t*)alloc((size_t)GG * 128 * 2);
  half_t* pair16 = (half_t*)alloc((size_t)GG * 128 * 2);
  (void)ws_size; (void)in_sizes; (void)n_in; (void)out_size;

  const int* esrc = ei;
  const int* edst = ei + EE;

  // 6 dispatches total (was 10 kernels + 2 memsets)
  prep_all<<<1984, 256, 0, stream>>>(W_l, W_r, W1, setix, Wt, W1p, slot_node, scnt);
  fused_mid<<<10496, 256, 0, stream>>>(x, Wt, b_l, slot_node, setix, esrc, edst,
                                       scnt, sbuf, y16, r_slot);
  slot_agg<<<SBUCK, 256, 0, stream>>>(sbuf, scnt, y16, r_slot, h_slot);
  s_pair_kernel<<<(GG * 128) / 256, 256, 0, stream>>>(ir, W_ir, b_ir, S16, h_slot, setix, pair16);
  biggemm<<<(GG / 128) * NSPLIT, 256, 0, stream>>>(pair16, S16, W1p, zpart);
  reduce_mlp<<<GG / 4, 256, 0, stream>>>(zpart, b1, W2, b2, out);
}

// Round 9
// 252.011 us; speedup vs baseline: 1.3090x; 1.0168x over previous
//
#include <hip/hip_runtime.h>

#define NN   131072      // nodes
#define GG   8192        // graphs
#define EE   2097152     // edges
#define KBIG 16384       // (2*GS)^2
#define NPAD 224         // 200 padded to 14*16 (2 waves x 7 nt)
#define NSPLIT 8
#define NSEL  16384      // selected slots (2 per graph)
#define SBUCK 1024       // slot buckets of 16 slots (4 blocks/CU in slot_agg)
#define SUBC  4          // sub-counters per bucket (atomic spread)
#define SCAPS 112        // per-sub capacity (mean ~59 + ~6.9 sigma)
#define SCAPT (SUBC*SCAPS)  // 448 per bucket

typedef _Float16 half_t;
typedef __attribute__((ext_vector_type(8))) _Float16 half8;
typedef __attribute__((ext_vector_type(4))) _Float16 half4;
typedef __attribute__((ext_vector_type(4))) float floatx4;

__device__ inline floatx4 mfma16(half8 a, half8 b, floatx4 c) {
  return __builtin_amdgcn_mfma_f32_16x16x32_f16(a, b, c, 0, 0, 0);
}

// ---------------- fused prep: W1p repack | Wt repack | slot_node | scnt zero ----------------
// blocks [0,1792): prep_w1p ; [1792,1856): prep_w ; [1856,1920): slot_node ; [1920,2176): scnt=0
__global__ __launch_bounds__(256) void prep_all(const float* __restrict__ Wl,
                                                const float* __restrict__ Wr,
                                                const float* __restrict__ W1,
                                                const int* __restrict__ setix,
                                                half_t* __restrict__ Wt,
                                                half_t* __restrict__ W1p,
                                                int* __restrict__ slot_node,
                                                int* __restrict__ scnt) {
  int b = blockIdx.x, tid = threadIdx.x;
  if (b < 1792) {
    // W1p packed fragment-order for phase-split K:
    // frag = (((split*2+ph)*16 + i)*2 + jj)*14 + nt ; within frag: lane, 8 elems
    int idx = b * 256 + tid;          // 8*2*16*2*14*64 = 458752
    int lane = idx & 63;
    int t = idx >> 6;
    int nt = t % 14; t /= 14;
    int jj = t & 1;  t >>= 1;
    int i  = t & 15; t >>= 4;
    int ph = t & 1;  t >>= 1;
    int split = t;
    int n = nt * 16 + (lane & 15);
    int k0 = split * 2048 + i * 128 + ph * 64 + jj * 32 + (lane >> 4) * 8;
    half8 v;
#pragma unroll
    for (int e = 0; e < 8; e++)
      v[e] = (half_t)((n < 200) ? W1[(size_t)(k0 + e) * 200 + n] : 0.f);
    *(half8*)(W1p + (size_t)idx * 8) = v;
  } else if (b < 1856) {
    // Wt[n][k] (n-major, f16): n<64 -> W_l[k][n], n>=64 -> W_r[k][n-64]
    int idx = (b - 1792) * 256 + tid; // 128*128
    int n = idx >> 7, k = idx & 127;
    float v = (n < 64) ? Wl[k * 64 + n] : Wr[k * 64 + (n - 64)];
    Wt[n * 128 + k] = (half_t)v;
  } else if (b < 1920) {
    int idx = (b - 1856) * 256 + tid; // 16384 slots
    slot_node[idx] = (idx >> 1) * 16 + setix[idx];
  } else {
    int idx = (b - 1920) * 256 + tid; // 65536 ints (SBUCK*SUBC*16)
    scnt[idx] = 0;
  }
}

// ---------------- fused mid: y_gemm | r_slots | filter_scatter ----------------
// blocks [0,2048): y = x@W_l ; [2048,2304): r_slot ; [2304,10496): edge filter.
// y-part epilogue: ybuf slices are per-wave private -> no __syncthreads, just
// lgkmcnt(0) (writes complete) + sched_barrier fence (rule 18).
__global__ __launch_bounds__(256) void fused_mid(const float* __restrict__ x,
                                                 const half_t* __restrict__ WtG,
                                                 const float* __restrict__ b_l,
                                                 const int* __restrict__ slot_node,
                                                 const int* __restrict__ setix,
                                                 const int* __restrict__ src,
                                                 const int* __restrict__ dst,
                                                 int* __restrict__ scnt,
                                                 unsigned int* __restrict__ sbuf,
                                                 half_t* __restrict__ y16,
                                                 half_t* __restrict__ r_slot) {
  __shared__ half_t wlds[64 * 128];   // y_gemm: W_l rows 0..63, 16 KB (cross-wave staged)
  __shared__ half_t ybuf[64 * 72];    // y_gemm: per-wave-private transpose slices
  int b = blockIdx.x, tid = threadIdx.x;
  if (b < 2048) {
    int w = tid >> 6, lane = tid & 63;
    int m = lane & 15, q = lane >> 4, kc = q * 8;
#pragma unroll
    for (int it = 0; it < 4; it++) {
      int cb = (it * 4 + w) * 64;
      const half_t* g = WtG + ((size_t)cb + lane) * 8;
      half_t* l = wlds + (size_t)cb * 8;
      __builtin_amdgcn_global_load_lds((const __attribute__((address_space(1))) uint32_t*)g,
                                       (__attribute__((address_space(3))) uint32_t*)l, 16, 0, 0);
    }
    int node0 = b * 64 + w * 16;
    float4 xu[4][2];
#pragma unroll
    for (int step = 0; step < 4; step++) {
      const float* xp = x + (size_t)(node0 + m) * 128 + step * 32 + kc;
      xu[step][0] = *(const float4*)xp;
      xu[step][1] = *(const float4*)(xp + 4);
    }
    __syncthreads();                  // wlds staged cooperatively -> barrier required
    floatx4 acc[4];
#pragma unroll
    for (int nt = 0; nt < 4; nt++) acc[nt] = (floatx4){0.f, 0.f, 0.f, 0.f};
#pragma unroll
    for (int step = 0; step < 4; step++) {
      float4 u0 = xu[step][0], u1 = xu[step][1];
      half8 av = {(half_t)u0.x, (half_t)u0.y, (half_t)u0.z, (half_t)u0.w,
                  (half_t)u1.x, (half_t)u1.y, (half_t)u1.z, (half_t)u1.w};
      int k0 = step * 32 + kc;
#pragma unroll
      for (int nt = 0; nt < 4; nt++) {
        half8 bv = *(const half8*)(wlds + (nt * 16 + m) * 128 + k0);
        acc[nt] = mfma16(av, bv, acc[nt]);
      }
    }
    // per-wave private transpose: rows [w*16, w*16+16) of ybuf only
#pragma unroll
    for (int nt = 0; nt < 4; nt++)
#pragma unroll
      for (int r = 0; r < 4; r++)
        ybuf[(w * 16 + q * 4 + r) * 72 + nt * 16 + m] = (half_t)acc[nt][r];
    asm volatile("s_waitcnt lgkmcnt(0)" ::: "memory");  // my ds_writes complete
    __builtin_amdgcn_sched_barrier(0);
#pragma unroll
    for (int it = 0; it < 2; it++) {
      int ch = lane + it * 64;        // 128 chunks of 16B per wave (16 rows x 8)
      int row = ch >> 3, co = (ch & 7) * 8;
      *(half8*)(y16 + (size_t)(node0 + row) * 64 + co) =
          *(const half8*)(ybuf + (w * 16 + row) * 72 + co);
    }
  } else if (b < 2304) {
    // r_slot[slot] = x[slot_node[slot]] @ W_r + b_l (16384 slots)
    int w = tid >> 6, lane = tid & 63;
    int m = lane & 15, q = lane >> 4, kc = q * 8;
    int s0 = (b - 2048) * 64 + w * 16;
    int node = slot_node[s0 + m];
    floatx4 acc[4];
#pragma unroll
    for (int nt = 0; nt < 4; nt++) acc[nt] = (floatx4){0.f, 0.f, 0.f, 0.f};
#pragma unroll
    for (int step = 0; step < 4; step++) {
      int k0 = step * 32 + kc;
      const float* xp = x + (size_t)node * 128 + k0;
      float4 u0 = *(const float4*)xp;
      float4 u1 = *(const float4*)(xp + 4);
      half8 av = {(half_t)u0.x, (half_t)u0.y, (half_t)u0.z, (half_t)u0.w,
                  (half_t)u1.x, (half_t)u1.y, (half_t)u1.z, (half_t)u1.w};
#pragma unroll
      for (int nt = 0; nt < 4; nt++) {
        half8 bv = *(const half8*)(WtG + (size_t)(64 + nt * 16 + m) * 128 + k0);
        acc[nt] = mfma16(av, bv, acc[nt]);
      }
    }
#pragma unroll
    for (int nt = 0; nt < 4; nt++) {
      int n = nt * 16 + m;
      float bias = b_l[n];
#pragma unroll
      for (int r = 0; r < 4; r++) {
        int s = s0 + q * 4 + r;
        r_slot[(size_t)s * 64 + n] = (half_t)(acc[nt][r] + bias);
      }
    }
  } else {
    // filter_scatter, arithmetic slot (si0-priority canonical); bucket = slot>>4
    int eb = b - 2304;
    int e = eb * 256 + tid;
    int d = dst[e];
    int g = d >> 4, local = d & 15;
    int si0 = setix[g * 2], si1 = setix[g * 2 + 1];
    int slot = (local == si0) ? g * 2 : ((local == si1) ? g * 2 + 1 : -1);
    if (slot >= 0) {
      int bk = slot >> 4;
      int sub = eb & (SUBC - 1);
      int pos = atomicAdd(&scnt[(bk * SUBC + sub) * 16], 1);
      if (pos < SCAPS)
        sbuf[(size_t)(bk * SUBC + sub) * SCAPS + pos] =
            (unsigned int)src[e] | ((unsigned int)(slot & 15) << 17);
    }
  }
}

// ---------------- per-slot SAGE agg: 1024 buckets x 16 slots, 16 threads/slot ----------------
// Was 256 blocks (1/CU, 12.5% occupancy, 4 thr/slot) -> latency-bound on random
// 128B y16-row reads. Now 4 blocks/CU, 16 thr/slot (half4 8B each, 16 thr cover the
// full 128B row): 4x block- and 4x thread-level parallelism on identical traffic.
__global__ __launch_bounds__(256) void slot_agg(const unsigned int* __restrict__ sbuf,
                                                const int* __restrict__ scnt,
                                                const half_t* __restrict__ y16,
                                                const half_t* __restrict__ r_slot,
                                                half_t* __restrict__ h_slot) {
  __shared__ int sorted[SCAPT];    // src indices, grouped by local slot (448)
  __shared__ int hist[16];
  __shared__ int base[16];
  __shared__ int start[17];
  int b = blockIdx.x, tid = threadIdx.x;
  if (tid < 16) hist[tid] = 0;
  __syncthreads();
  unsigned int myedge[SUBC];
  int mycnt = 0;
#pragma unroll
  for (int sub = 0; sub < SUBC; sub++) {
    int n = scnt[(b * SUBC + sub) * 16]; if (n > SCAPS) n = SCAPS;
    const unsigned int* eb = sbuf + (size_t)(b * SUBC + sub) * SCAPS;
    for (int e = tid; e < n; e += 256) {   // n<=112 -> at most 1 per sub
      unsigned int pk = eb[e];
      myedge[mycnt++] = pk;
      atomicAdd(&hist[pk >> 17], 1);
    }
  }
  __syncthreads();
  if (tid < 16) {                       // lane 0..15: exclusive scan of 16 bins
    int v = hist[tid];
    int sum = v;
#pragma unroll
    for (int off = 1; off < 16; off <<= 1) {
      int u = __shfl_up(sum, off);
      if (tid >= off) sum += u;
    }
    start[tid] = sum - v;
    base[tid]  = sum - v;
    if (tid == 15) start[16] = sum;
  }
  __syncthreads();
  for (int i = 0; i < mycnt; i++) {
    unsigned int pk = myedge[i];
    int pos = atomicAdd(&base[pk >> 17], 1);
    sorted[pos] = (int)(pk & 0x1FFFF);
  }
  __syncthreads();
  // 16 threads/slot, 4 cols each (half4)
  int s = tid >> 4, p = tid & 15;
  int e0 = start[s], e1 = start[s + 1];
  float a0 = 0.f, a1 = 0.f, a2 = 0.f, a3 = 0.f;
  int e = e0;
  for (; e + 2 <= e1; e += 2) {
    int n0 = sorted[e], n1 = sorted[e + 1];
    half4 v0 = *(const half4*)(y16 + (size_t)n0 * 64 + p * 4);
    half4 v1 = *(const half4*)(y16 + (size_t)n1 * 64 + p * 4);
    a0 += (float)v0[0] + (float)v1[0];
    a1 += (float)v0[1] + (float)v1[1];
    a2 += (float)v0[2] + (float)v1[2];
    a3 += (float)v0[3] + (float)v1[3];
  }
  if (e < e1) {
    int n0 = sorted[e];
    half4 v0 = *(const half4*)(y16 + (size_t)n0 * 64 + p * 4);
    a0 += (float)v0[0]; a1 += (float)v0[1]; a2 += (float)v0[2]; a3 += (float)v0[3];
  }
  int slot = b * 16 + s;
  float inv = 1.0f / fmaxf((float)(e1 - e0), 1.0f);
  half4 rr = *(const half4*)(r_slot + (size_t)slot * 64 + p * 4);
  half4 o;
  o[0] = (half_t)fmaxf(a0 * inv + (float)rr[0], 0.f);
  o[1] = (half_t)fmaxf(a1 * inv + (float)rr[1], 0.f);
  o[2] = (half_t)fmaxf(a2 * inv + (float)rr[2], 0.f);
  o[3] = (half_t)fmaxf(a3 * inv + (float)rr[3], 0.f);
  *(half4*)(h_slot + (size_t)slot * 64 + p * 4) = o;
}

// ---------------- S = relu(ir @ W_ir + b_ir) and pair gather from h_slot ----------------
__global__ void s_pair_kernel(const float* __restrict__ ir, const float* __restrict__ W_ir,
                              const float* __restrict__ b_ir, half_t* __restrict__ S16,
                              const half_t* __restrict__ h_slot,
                              const int* __restrict__ set_idx, half_t* __restrict__ pair16) {
  int idx = blockIdx.x * blockDim.x + threadIdx.x; // G*128
  int g = idx >> 7, o = idx & 127;
  const float* irow = ir + g * 32;
  float sv = b_ir[o];
#pragma unroll
  for (int a = 0; a < 32; a++) sv += irow[a] * W_ir[a * 128 + o];
  S16[idx] = (half_t)fmaxf(sv, 0.f);
  int which = o >> 6, c = o & 63;
  int li = set_idx[g * 2 + which];
  // same si0-priority canonical slot as filter_scatter
  int slot = (li == set_idx[g * 2]) ? g * 2 : g * 2 + 1;
  pair16[idx] = h_slot[(size_t)slot * 64 + c];
}

// ---------------- z-partials: (pair(x)S) @ W1, split-K=8, BM=128 ----------------
// Round-7 version (unchanged): 2x2 wave grid, reuse-4, sf[4][2] phase-split,
// counted-vmcnt T3/T4 pipelining, 2 stage-units in flight.
__global__ __launch_bounds__(256, 2) void biggemm(const half_t* __restrict__ pair16,
                                                  const half_t* __restrict__ S16,
                                                  const half_t* __restrict__ W1p,
                                                  float* __restrict__ zpart) {
  __shared__ __align__(16) half_t bbuf[2][28 * 512];   // 57344 B, 2 step-units
  __shared__ half_t pls[16][128];                      // 4096 B
  int bx = blockIdx.x;
  int mt = bx >> 3, split = bx & 7;   // split == XCD id -> W1 slice L2-resident per XCD
  int g0 = mt * 128;
  int tid = threadIdx.x, w = tid >> 6, lane = tid & 63;
  int wm = w >> 1, wn = w & 1;        // 2x2 wave grid
  int m = lane & 15, q = lane >> 4, kc = q * 8;
  int ntb = wn * 7;                   // this wave's nt base (7 nt groups)

  auto stage = [&](int s, int buf) {
#pragma unroll
    for (int ff = 0; ff < 7; ff++) {
      int f = ff * 4 + w;             // 28 = 7 x 4 waves
      const half_t* gsrc = W1p + (((size_t)(split * 32 + s) * 28) + f) * 512 + lane * 8;
      half_t* ldst = &bbuf[buf][f * 512];
      __builtin_amdgcn_global_load_lds((const __attribute__((address_space(1))) uint32_t*)gsrc,
                                       (__attribute__((address_space(3))) uint32_t*)ldst, 16, 0, 0);
    }
  };

  {
    int row = tid & 127, sel = tid >> 7;
    half8 pa = *(const half8*)(pair16 + (size_t)(g0 + row) * 128 + split * 16 + sel * 8);
#pragma unroll
    for (int j = 0; j < 8; j++) pls[sel * 8 + j][row] = pa[j];
  }
  __syncthreads();                     // pls visible (one-time prologue drain)

  stage(0, 0);                         // 7 outstanding
  stage(1, 1);                         // 14 outstanding

  floatx4 acc[4][7];
#pragma unroll
  for (int sb = 0; sb < 4; sb++)
#pragma unroll
    for (int t = 0; t < 7; t++) acc[sb][t] = (floatx4){0.f, 0.f, 0.f, 0.f};

  half8 sf[4][2];   // only current phase's S-fragment block lives in registers
#pragma unroll
  for (int ph = 0; ph < 2; ph++) {
#pragma unroll
    for (int sub = 0; sub < 4; sub++) {
      int grow = g0 + wm * 64 + sub * 16 + m;
#pragma unroll
      for (int j2 = 0; j2 < 2; j2++)
        sf[sub][j2] = *(const half8*)(S16 + (size_t)grow * 128 + ph * 64 + j2 * 32 + kc);
    }
#pragma unroll
    for (int i = 0; i < 16; i++) {
      const int s = ph * 16 + i;
      const int cur = s & 1;
      if (ph == 1 && i == 15) {
        asm volatile("s_waitcnt vmcnt(0)" ::: "memory");
      } else {
        asm volatile("s_waitcnt vmcnt(7)" ::: "memory");
      }
      __builtin_amdgcn_sched_barrier(0);
      __builtin_amdgcn_s_barrier();    // all waves' stage-s loads complete
      __builtin_amdgcn_sched_barrier(0);

      half_t p0 = pls[i][wm * 64 + 0 * 16 + m];
      half_t p1 = pls[i][wm * 64 + 1 * 16 + m];
      half_t p2 = pls[i][wm * 64 + 2 * 16 + m];
      half_t p3 = pls[i][wm * 64 + 3 * 16 + m];
      const half_t* bb = bbuf[cur];
#pragma unroll
      for (int jj = 0; jj < 2; jj++) {
        half8 a0 = sf[0][jj] * p0;
        half8 a1 = sf[1][jj] * p1;
        half8 a2 = sf[2][jj] * p2;
        half8 a3 = sf[3][jj] * p3;
#pragma unroll
        for (int t = 0; t < 7; t++) {
          half8 bv = *(const half8*)(bb + (jj * 14 + ntb + t) * 512 + lane * 8);
          acc[0][t] = mfma16(a0, bv, acc[0][t]);
          acc[1][t] = mfma16(a1, bv, acc[1][t]);
          acc[2][t] = mfma16(a2, bv, acc[2][t]);
          acc[3][t] = mfma16(a3, bv, acc[3][t]);
        }
      }

      if (s < 30) {
        __builtin_amdgcn_sched_barrier(0);
        __builtin_amdgcn_s_barrier();
        __builtin_amdgcn_sched_barrier(0);
        stage(s + 2, cur);             // back to 14 outstanding
      }
    }
  }

#pragma unroll
  for (int sub = 0; sub < 4; sub++)
#pragma unroll
    for (int t = 0; t < 7; t++)
#pragma unroll
      for (int r = 0; r < 4; r++) {
        int row = g0 + wm * 64 + sub * 16 + q * 4 + r;
        zpart[((size_t)split * GG + row) * NPAD + (ntb + t) * 16 + m] = acc[sub][t][r];
      }
}

// ---------------- split-K reduce + b1 + relu + (200->2) GEMM + b2 ----------------
__global__ __launch_bounds__(256) void reduce_mlp(const float* __restrict__ zpart,
                                                  const float* __restrict__ b1,
                                                  const float* __restrict__ W2,
                                                  const float* __restrict__ b2,
                                                  float* __restrict__ out) {
  int tid = threadIdx.x;
  int w = tid >> 6, lane = tid & 63;
  int g = blockIdx.x * 4 + w;
  float p0 = 0.f, p1 = 0.f;
#pragma unroll
  for (int qq = 0; qq < 4; qq++) {
    int c = qq * 64 + lane;
    if (c < 200) {
      float z = 0.f;
#pragma unroll
      for (int sp = 0; sp < NSPLIT; sp++)
        z += zpart[((size_t)sp * GG + g) * NPAD + c];
      z += b1[c];
      z = fmaxf(z, 0.f);
      p0 += z * W2[c * 2];
      p1 += z * W2[c * 2 + 1];
    }
  }
#pragma unroll
  for (int off = 32; off; off >>= 1) {
    p0 += __shfl_down(p0, off);
    p1 += __shfl_down(p1, off);
  }
  if (lane == 0) {
    out[g * 2] = p0 + b2[0];
    out[g * 2 + 1] = p1 + b2[1];
  }
}

extern "C" void kernel_launch(void* const* d_in, const int* in_sizes, int n_in,
                              void* d_out, int out_size, void* d_ws, size_t ws_size,
                              hipStream_t stream) {
  const float* x     = (const float*)d_in[0];
  const int*   ei    = (const int*)d_in[1];
  const int*   setix = (const int*)d_in[2];
  const float* ir    = (const float*)d_in[4];
  const float* W_l   = (const float*)d_in[5];
  const float* b_l   = (const float*)d_in[6];
  const float* W_r   = (const float*)d_in[7];
  const float* W_ir  = (const float*)d_in[8];
  const float* b_ir  = (const float*)d_in[9];
  const float* W1    = (const float*)d_in[10];
  const float* b1    = (const float*)d_in[11];
  const float* W2    = (const float*)d_in[12];
  const float* b2    = (const float*)d_in[13];
  float* out = (float*)d_out;

  char* ws = (char*)d_ws;
  size_t off = 0;
  auto alloc = [&](size_t bytes) -> void* {
    void* p = ws + off;
    off = (off + bytes + 255) & ~(size_t)255;
    return p;
  };
  // ---- pool: everything here is dead before biggemm; zpart aliases it ----
  size_t pool_start = off;
  int* slot_node = (int*)alloc((size_t)NSEL * 4);                     // 64 KB
  int* scnt      = (int*)alloc((size_t)SBUCK * SUBC * 16 * 4);        // 256 KB (padded counters)
  unsigned int* sbuf = (unsigned int*)alloc((size_t)SBUCK * SUBC * SCAPS * 4); // 1.79 MB
  half_t* y16    = (half_t*)alloc((size_t)NN * 64 * 2);               // 16 MB
  half_t* r_slot = (half_t*)alloc((size_t)NSEL * 64 * 2);             // 2 MB
  half_t* h_slot = (half_t*)alloc((size_t)NSEL * 64 * 2);             // 2 MB
  float* zpart = (float*)(ws + pool_start);
  {  // ensure zpart (58.7 MB) fits inside the dead pool region
    size_t zend = pool_start + (((size_t)NSPLIT * GG * NPAD * 4 + 255) & ~(size_t)255);
    if (off < zend) off = zend;
  }
  // ---- live through biggemm ----
  half_t* Wt     = (half_t*)alloc(128 * 128 * 2);
  half_t* W1p    = (half_t*)alloc((size_t)NPAD * KBIG * 2);
  half_t* S16    = (half_t*)alloc((size_t)GG * 128 * 2);
  half_t* pair16 = (half_t*)alloc((size_t)GG * 128 * 2);
  (void)ws_size; (void)in_sizes; (void)n_in; (void)out_size;

  const int* esrc = ei;
  const int* edst = ei + EE;

  // 6 dispatches
  prep_all<<<2176, 256, 0, stream>>>(W_l, W_r, W1, setix, Wt, W1p, slot_node, scnt);
  fused_mid<<<10496, 256, 0, stream>>>(x, Wt, b_l, slot_node, setix, esrc, edst,
                                       scnt, sbuf, y16, r_slot);
  slot_agg<<<SBUCK, 256, 0, stream>>>(sbuf, scnt, y16, r_slot, h_slot);
  s_pair_kernel<<<(GG * 128) / 256, 256, 0, stream>>>(ir, W_ir, b_ir, S16, h_slot, setix, pair16);
  biggemm<<<(GG / 128) * NSPLIT, 256, 0, stream>>>(pair16, S16, W1p, zpart);
  reduce_mlp<<<GG / 4, 256, 0, stream>>>(zpart, b1, W2, b2, out);
}